// Round 6
// baseline (256.040 us; speedup 1.0000x reference)
//
#include <hip/hip_runtime.h>
#include <hip/hip_bf16.h>

#define SS 4096
#define NROW 16384

typedef __attribute__((ext_vector_type(8))) short short8;
typedef __attribute__((ext_vector_type(4))) float f32x4;

static __device__ __forceinline__ short f2bf(float f) {           // RNE
    union { float f; unsigned u; } v; v.f = f;
    unsigned r = v.u + 0x7FFFu + ((v.u >> 16) & 1u);
    return (short)(r >> 16);
}
static __device__ __forceinline__ short f2bf_fast(float f) {      // round-half-up
    union { float f; unsigned u; } v; v.f = f;
    return (short)((v.u + 0x8000u) >> 16);
}
static __device__ __forceinline__ unsigned pkbf(float lo, float hi) {
    union { float f; unsigned u; } x, y; x.f = lo; y.f = hi;
    return __builtin_amdgcn_perm(y.u + 0x8000u, x.u + 0x8000u, 0x07060302);
}
static __device__ __forceinline__ float bf2f(short s) {
    union { unsigned u; float f; } v;
    v.u = ((unsigned)(unsigned short)s) << 16;
    return v.f;
}

// ---------------- pack W: [1024][64] fp32 x3 -> Wpack[n=192][k=1024] bf16 (LDS transpose) ----------------
__global__ __launch_bounds__(256) void pack_w(const float* __restrict__ Wq,
                                              const float* __restrict__ Wk,
                                              const float* __restrict__ Wv,
                                              short* __restrict__ Wpack) {
    __shared__ float T[64 * 65];
    int bid = blockIdx.x;                 // 48 = 3 n-blocks x 16 k-blocks
    int nb = bid >> 4, kb = bid & 15;
    const float* W = (nb == 0) ? Wq : (nb == 1 ? Wk : Wv);
    int n0 = nb * 64, k0 = kb * 64;
    int tid = threadIdx.x;
    for (int ps = 0; ps < 16; ++ps) {
        int idx = tid + ps * 256;
        int kk = idx >> 6, nn = idx & 63;
        T[kk * 65 + nn] = W[(k0 + kk) * 64 + nn];
    }
    __syncthreads();
    for (int ps = 0; ps < 16; ++ps) {
        int idx = tid + ps * 256;
        int nn = idx >> 6, kk = idx & 63;
        Wpack[(n0 + nn) * 1024 + k0 + kk] = f2bf(T[kk * 65 + nn]);
    }
}

// ---------- proj: register-direct, no LDS, no barriers. 1024 blocks x 4 waves. ----------
// wave = 16 rows x 48 cols; A-frags from x (fp32->bf16 in reg), B-frags from Wpack rows.
__global__ __launch_bounds__(256, 4) void proj_qkv(const float* __restrict__ x,
                                                   const short* __restrict__ Wpack,
                                                   const float* __restrict__ bq,
                                                   const float* __restrict__ bk,
                                                   const float* __restrict__ bv,
                                                   short* __restrict__ Qg,
                                                   short* __restrict__ Kg,
                                                   short* __restrict__ Vt) {
    int tid = threadIdx.x, lane = tid & 63, wv = tid >> 6;
    int g = lane >> 4, c = lane & 15;
    int rowbase = blockIdx.x * 16;
    int col0 = wv * 48;

    f32x4 acc[3];
    for (int i = 0; i < 3; ++i) acc[i] = (f32x4)(0.f);

    const float* xr = x + (rowbase + c) * 1024 + g * 8;          // A row = c
    const short* wr = Wpack + (col0 + c) * 1024 + g * 8;         // B row = col0 + nt*16 + c

    float4 xa = *reinterpret_cast<const float4*>(xr);
    float4 xb = *reinterpret_cast<const float4*>(xr + 4);
    short8 bcur[3];
#pragma unroll
    for (int nt = 0; nt < 3; ++nt)
        bcur[nt] = *reinterpret_cast<const short8*>(wr + nt * 16384);

    for (int ko = 0; ko < 32; ++ko) {
        short8 a;
        unsigned* aw = (unsigned*)&a;
        aw[0] = pkbf(xa.x, xa.y); aw[1] = pkbf(xa.z, xa.w);
        aw[2] = pkbf(xb.x, xb.y); aw[3] = pkbf(xb.z, xb.w);
        short8 bnext[3];
        if (ko < 31) {
            int k1 = (ko + 1) * 32;
            xa = *reinterpret_cast<const float4*>(xr + k1);
            xb = *reinterpret_cast<const float4*>(xr + k1 + 4);
#pragma unroll
            for (int nt = 0; nt < 3; ++nt)
                bnext[nt] = *reinterpret_cast<const short8*>(wr + nt * 16384 + k1);
        }
#pragma unroll
        for (int nt = 0; nt < 3; ++nt)
            acc[nt] = __builtin_amdgcn_mfma_f32_16x16x32_bf16(a, bcur[nt], acc[nt], 0, 0, 0);
#pragma unroll
        for (int nt = 0; nt < 3; ++nt) bcur[nt] = bnext[nt];
    }

    const float SCQ = 0.125f * 1.4426950408889634f;   // fold score scale + log2e into Q
#pragma unroll
    for (int nt = 0; nt < 3; ++nt) {
        int col = col0 + nt * 16 + c;
        for (int r = 0; r < 4; ++r) {
            int grow = rowbase + g * 4 + r;
            float vv = acc[nt][r];
            if (col < 64) {
                Qg[grow * 64 + col] = f2bf((vv + bq[col]) * SCQ);
            } else if (col < 128) {
                Kg[grow * 64 + (col - 64)] = f2bf(vv + bk[col - 64]);
            } else {
                int f = col - 128;
                int batch = grow >> 12, s = grow & 4095;
                Vt[batch * 262144 + (s >> 6) * 4096 + f * 64 + (s & 63)] = f2bf(vv + bv[f]);
            }
        }
    }
}

// ---------- attn: register-direct K/V, ZERO barriers, fixed-max softmax, exact grid ----------
// Block = 4 independent waves on one (batch, p, chunk); wave wv owns q-rows p*64+wv*16..
__global__ __launch_bounds__(256, 4) void attn(const short* __restrict__ Qg,
                                               const short* __restrict__ Kg,
                                               const short* __restrict__ Vt,
                                               short* __restrict__ Opart,
                                               float* __restrict__ Ls) {
    __shared__ short Ps[4][16 * 68];
    int tid = threadIdx.x, lane = tid & 63, wv = tid >> 6;
    int g = lane >> 4, c = lane & 15;

    // reversed decode: biggest-p blocks dispatch first (tail = cheap blocks)
    int rb = 1151 - blockIdx.x;
    int batch = rb / 288;
    int j = rb - batch * 288;
    int gq = (int)((sqrtf((float)j + 1.0f) - 1.0f) * 0.5f);
    while (4 * (gq + 1) * (gq + 2) <= j) ++gq;
    while (4 * gq * (gq + 1) > j) --gq;
    int rem = j - 4 * gq * (gq + 1);
    int pidx = rem / (gq + 1);
    int ch = rem - pidx * (gq + 1);
    int p = gq * 8 + pidx;

    int t0 = ch * 8, t1 = min(t0 + 8, p + 1);
    int qrow0 = batch * SS + p * 64;
    const short* KbL = Kg + batch * SS * 64 + c * 64 + g * 8;   // B-frag base: key=nt*16+c
    const short* VbL = Vt + batch * SS * 64 + c * 64 + g * 8;   // B-frag base: f=ft*16+c

    short8 aq0 = *reinterpret_cast<const short8*>(Qg + (qrow0 + wv * 16 + c) * 64 + g * 8);
    short8 aq1 = *reinterpret_cast<const short8*>(Qg + (qrow0 + wv * 16 + c) * 64 + 32 + g * 8);

    f32x4 acc_o[4];
    for (int f = 0; f < 4; ++f) acc_o[f] = (f32x4)(0.f);
    float rs[4] = {0.f, 0.f, 0.f, 0.f};
    short* Psw = Ps[wv];

    short8 kf[8];
#pragma unroll
    for (int i = 0; i < 8; ++i)   // i = kc*4 + nt
        kf[i] = *reinterpret_cast<const short8*>(KbL + t0 * 4096 + (i & 3) * 1024 + (i >> 2) * 32);

    for (int t = t0; t < t1; ++t) {
        // S = Q K^T on prefetched K-frags
        f32x4 s[4];
#pragma unroll
        for (int nt = 0; nt < 4; ++nt) {
            s[nt] = (f32x4)(0.f);
            s[nt] = __builtin_amdgcn_mfma_f32_16x16x32_bf16(aq0, kf[nt], s[nt], 0, 0, 0);
            s[nt] = __builtin_amdgcn_mfma_f32_16x16x32_bf16(aq1, kf[4 + nt], s[nt], 0, 0, 0);
        }
        // issue V loads (this tile) — consumed after softmax
        short8 vf[8];
#pragma unroll
        for (int i = 0; i < 8; ++i)   // i = kc2*4 + ft
            vf[i] = *reinterpret_cast<const short8*>(VbL + t * 4096 + (i & 3) * 1024 + (i >> 2) * 32);
        // issue K loads (next tile) — consumed next iteration
        if (t + 1 < t1) {
#pragma unroll
            for (int i = 0; i < 8; ++i)
                kf[i] = *reinterpret_cast<const short8*>(KbL + (t + 1) * 4096 + (i & 3) * 1024 + (i >> 2) * 32);
        }

        // fixed-max softmax: p = exp2(s) (Q pre-scaled by 1/8*log2e)
        if (t == p) {       // diagonal tile: causal mask
#pragma unroll
            for (int nt = 0; nt < 4; ++nt)
                for (int r = 0; r < 4; ++r) {
                    int key = nt * 16 + c;
                    int row = wv * 16 + g * 4 + r;
                    float pv = (key <= row) ? __builtin_amdgcn_exp2f(s[nt][r]) : 0.f;
                    rs[r] += pv;
                    Psw[(g * 4 + r) * 68 + nt * 16 + c] = f2bf_fast(pv);
                }
        } else {
#pragma unroll
            for (int nt = 0; nt < 4; ++nt)
                for (int r = 0; r < 4; ++r) {
                    float pv = __builtin_amdgcn_exp2f(s[nt][r]);
                    rs[r] += pv;
                    Psw[(g * 4 + r) * 68 + nt * 16 + c] = f2bf_fast(pv);
                }
        }

        // O += P V  (P round-trips wave-private LDS; V frags from global)
#pragma unroll
        for (int kc2 = 0; kc2 < 2; ++kc2) {
            short8 ap = *reinterpret_cast<const short8*>(&Psw[c * 68 + kc2 * 32 + g * 8]);
#pragma unroll
            for (int ft = 0; ft < 4; ++ft)
                acc_o[ft] = __builtin_amdgcn_mfma_f32_16x16x32_bf16(ap, vf[kc2 * 4 + ft], acc_o[ft], 0, 0, 0);
        }
    }

    // deferred l reduction over key-lanes (bits 0-3 of lane)
    float l[4];
#pragma unroll
    for (int r = 0; r < 4; ++r) {
        float ss = rs[r];
        ss += __shfl_xor(ss, 1);
        ss += __shfl_xor(ss, 2);
        ss += __shfl_xor(ss, 4);
        ss += __shfl_xor(ss, 8);
        l[r] = ss;
    }

    int slot = ((batch * 64 + p) << 3) + ch;
    short* op = Opart + slot * 4096;
#pragma unroll
    for (int r = 0; r < 4; ++r) {
        float inv = 1.0f / l[r];
        int row = wv * 16 + g * 4 + r;
        for (int ft = 0; ft < 4; ++ft)
            op[row * 64 + ft * 16 + c] = f2bf(acc_o[ft][r] * inv);
    }
    if (c == 0)
#pragma unroll
        for (int r = 0; r < 4; ++r)
            Ls[slot * 64 + wv * 16 + g * 4 + r] = l[r];
}

// ---------- merge <=8 chunks per (batch,P): out = sum(l_i * O_i) / sum(l_i) ----------
__global__ __launch_bounds__(256) void merge_k(const short* __restrict__ Opart,
                                               const float* __restrict__ Ls,
                                               float* __restrict__ out) {
    int bP = blockIdx.x;               // batch*64 + P
    int P = bP & 63, batch = bP >> 6;
    int nch = (P + 8) >> 3;            // ceil((P+1)/8)
    int tid = threadIdx.x;
    int row = tid & 63, fg = tid >> 6;
    int slot0 = bP << 3;

    float w[8];
    float wsum = 0.f;
    for (int i = 0; i < nch; ++i) { w[i] = Ls[(slot0 + i) * 64 + row]; wsum += w[i]; }
    float invw = 1.0f / wsum;

    float o[16];
    for (int jj = 0; jj < 16; ++jj) o[jj] = 0.f;
    for (int i = 0; i < nch; ++i) {
        const short* op = Opart + (slot0 + i) * 4096 + row * 64 + fg * 16;
        short8 v0 = *reinterpret_cast<const short8*>(op);
        short8 v1 = *reinterpret_cast<const short8*>(op + 8);
        for (int jj = 0; jj < 8; ++jj) {
            o[jj]     += w[i] * bf2f(v0[jj]);
            o[8 + jj] += w[i] * bf2f(v1[jj]);
        }
    }
    int orow = batch * SS + P * 64 + row;
    for (int jj = 0; jj < 16; jj += 4) {
        float4 v;
        v.x = o[jj] * invw; v.y = o[jj + 1] * invw; v.z = o[jj + 2] * invw; v.w = o[jj + 3] * invw;
        *reinterpret_cast<float4*>(out + orow * 64 + fg * 16 + jj) = v;
    }
}

extern "C" void kernel_launch(void* const* d_in, const int* in_sizes, int n_in,
                              void* d_out, int out_size, void* d_ws, size_t ws_size,
                              hipStream_t stream) {
    const float* x  = (const float*)d_in[0];
    const float* Wq = (const float*)d_in[1];
    const float* bq = (const float*)d_in[2];
    const float* Wk = (const float*)d_in[3];
    const float* bk = (const float*)d_in[4];
    const float* Wv = (const float*)d_in[5];
    const float* bv = (const float*)d_in[6];
    float* out = (float*)d_out;

    short* Wpack = (short*)d_ws;                    // 196608 shorts
    short* Qg    = Wpack + 196608;                  // 1048576
    short* Kg    = Qg + NROW * 64;                  // 1048576
    short* Vt    = Kg + NROW * 64;                  // 1048576 (tile-blocked [b][tile64][f][64])
    short* Opart = Vt + NROW * 64;                  // 2048*4096
    float* Ls    = (float*)(Opart + 2048 * 4096);   // 2048*64 floats

    hipLaunchKernelGGL(pack_w,   dim3(48),   dim3(256), 0, stream, Wq, Wk, Wv, Wpack);
    hipLaunchKernelGGL(proj_qkv, dim3(1024), dim3(256), 0, stream, x, Wpack, bq, bk, bv, Qg, Kg, Vt);
    hipLaunchKernelGGL(attn,     dim3(1152), dim3(256), 0, stream, Qg, Kg, Vt, Opart, Ls);
    hipLaunchKernelGGL(merge_k,  dim3(256),  dim3(256), 0, stream, Opart, Ls, out);
}

// Round 7
// 152.104 us; speedup vs baseline: 1.6833x; 1.6833x over previous
//
#include <hip/hip_runtime.h>
#include <hip/hip_bf16.h>

#define SS 4096
#define NROW 16384

typedef __attribute__((ext_vector_type(8))) short short8;
typedef __attribute__((ext_vector_type(4))) float f32x4;
typedef _Float16 half4 __attribute__((ext_vector_type(4)));

#define AS1 __attribute__((address_space(1)))
#define AS3 __attribute__((address_space(3)))

static __device__ __forceinline__ void glds16(const void* g, void* l) {
    __builtin_amdgcn_global_load_lds((const AS1 unsigned*)g, (AS3 unsigned*)l, 16, 0, 0);
}
static __device__ __forceinline__ short f2bf(float f) {           // RNE
    union { float f; unsigned u; } v; v.f = f;
    unsigned r = v.u + 0x7FFFu + ((v.u >> 16) & 1u);
    return (short)(r >> 16);
}
static __device__ __forceinline__ unsigned pkbf(float lo, float hi) {
    union { float f; unsigned u; } x, y; x.f = lo; y.f = hi;
    return __builtin_amdgcn_perm(y.u + 0x8000u, x.u + 0x8000u, 0x07060302);
}
static __device__ __forceinline__ float bf2f(short s) {
    union { unsigned u; float f; } v;
    v.u = ((unsigned)(unsigned short)s) << 16;
    return v.f;
}

// ---------------- pack W: [1024][64] fp32 x3 -> Wpack[n=192][k=1024] bf16 (LDS transpose) ----------------
__global__ __launch_bounds__(256) void pack_w(const float* __restrict__ Wq,
                                              const float* __restrict__ Wk,
                                              const float* __restrict__ Wv,
                                              short* __restrict__ Wpack) {
    __shared__ float T[64 * 65];
    int bid = blockIdx.x;                 // 48 = 3 n-blocks x 16 k-blocks
    int nb = bid >> 4, kb = bid & 15;
    const float* W = (nb == 0) ? Wq : (nb == 1 ? Wk : Wv);
    int n0 = nb * 64, k0 = kb * 64;
    int tid = threadIdx.x;
    for (int ps = 0; ps < 16; ++ps) {
        int idx = tid + ps * 256;
        int kk = idx >> 6, nn = idx & 63;
        T[kk * 65 + nn] = W[(k0 + kk) * 64 + nn];
    }
    __syncthreads();
    for (int ps = 0; ps < 16; ++ps) {
        int idx = tid + ps * 256;
        int nn = idx >> 6, kk = idx & 63;
        Wpack[(n0 + nn) * 1024 + k0 + kk] = f2bf(T[kk * 65 + nn]);
    }
}

// ---------- proj: 512 blocks x 256 thr; 32 rows x 192 cols; BK=64; glds double-buffer ----------
// (R5 structure — confirmed best) x staged fp32 via glds (source-swizzled); W staged bf16 via glds.
// V output: f16, tile-blocked [b][tile64][feat][64] with key XOR-swizzled by 4*(feat&15).
__global__ __launch_bounds__(256, 2) void proj_qkv(const float* __restrict__ x,
                                                   const short* __restrict__ Wpack,
                                                   const float* __restrict__ bq,
                                                   const float* __restrict__ bk,
                                                   const float* __restrict__ bv,
                                                   short* __restrict__ Qg,
                                                   short* __restrict__ Kg,
                                                   short* __restrict__ Vt) {
    __shared__ float Xs[2][32 * 64];
    __shared__ short Wsm[2][192 * 64];
    int tid = threadIdx.x, lane = tid & 63, wv = tid >> 6;
    int g = lane >> 4, c = lane & 15;
    int mh = wv & 1, nh = wv >> 1;
    int rowbase = blockIdx.x * 32;

    f32x4 acc[6];
    for (int i = 0; i < 6; ++i) acc[i] = (f32x4)(0.f);

    int xs0 = (wv * 2 + 0) * 64 + lane, xs1 = (wv * 2 + 1) * 64 + lane;
    int xr0 = xs0 >> 4, xp0 = (xs0 & 15) ^ (xr0 & 15);
    int xr1 = xs1 >> 4, xp1 = (xs1 & 15) ^ (xr1 & 15);

#define PROJ_ISSUE(nbs, k0)                                                              \
    do {                                                                                 \
        glds16(x + (rowbase + xr0) * 1024 + (k0) + xp0 * 4, &Xs[nbs][(wv * 2 + 0) * 256]); \
        glds16(x + (rowbase + xr1) * 1024 + (k0) + xp1 * 4, &Xs[nbs][(wv * 2 + 1) * 256]); \
        for (int j = 0; j < 6; ++j) {                                                    \
            int ws = (wv * 6 + j) * 64 + lane;                                           \
            int wr = ws >> 3, wp = (ws & 7) ^ (wr & 7);                                  \
            glds16(Wpack + wr * 1024 + (k0) + wp * 8, &Wsm[nbs][(wv * 6 + j) * 512]);    \
        }                                                                                \
    } while (0)

    PROJ_ISSUE(0, 0);

    for (int ko = 0; ko < 16; ++ko) {
        int bs = ko & 1;
        __syncthreads();
        if (ko < 15) PROJ_ISSUE(bs ^ 1, (ko + 1) * 64);
        for (int kc = 0; kc < 2; ++kc) {
            int h0 = kc * 8 + g * 2;
            float4 xa = *reinterpret_cast<const float4*>(&Xs[bs][(mh * 16 + c) * 64 + ((h0) ^ c) * 4]);
            float4 xb = *reinterpret_cast<const float4*>(&Xs[bs][(mh * 16 + c) * 64 + ((h0 + 1) ^ c) * 4]);
            short8 a;
            unsigned* aw = (unsigned*)&a;
            aw[0] = pkbf(xa.x, xa.y); aw[1] = pkbf(xa.z, xa.w);
            aw[2] = pkbf(xb.x, xb.y); aw[3] = pkbf(xb.z, xb.w);
            for (int nt = 0; nt < 6; ++nt) {
                int wrow = nh * 96 + nt * 16 + c;
                short8 b = *reinterpret_cast<const short8*>(&Wsm[bs][wrow * 64 + ((g + 4 * kc) ^ (c & 7)) * 8]);
                acc[nt] = __builtin_amdgcn_mfma_f32_16x16x32_bf16(a, b, acc[nt], 0, 0, 0);
            }
        }
    }
#undef PROJ_ISSUE

    const float SCQ = 0.125f * 1.4426950408889634f;   // fold score scale + log2e into Q
    _Float16* Vh = (_Float16*)Vt;
    for (int nt = 0; nt < 6; ++nt) {
        int col = nh * 96 + nt * 16 + c;
        for (int r = 0; r < 4; ++r) {
            int grow = rowbase + mh * 16 + g * 4 + r;
            float vv = acc[nt][r];
            if (col < 64) {
                Qg[grow * 64 + col] = f2bf((vv + bq[col]) * SCQ);
            } else if (col < 128) {
                Kg[grow * 64 + (col - 64)] = f2bf(vv + bk[col - 64]);
            } else {
                int f = col - 128;
                int batch = grow >> 12, s = grow & 4095;
                int key = s & 63;
                // f16, tile-blocked, key XOR-swizzled for conflict-free A-frag LDS reads in attn
                Vh[batch * 262144 + (s >> 6) * 4096 + f * 64 + (key ^ ((f & 15) * 4))] =
                    (_Float16)(vv + bv[f]);
            }
        }
    }
}

// ---------- attn: glds-staged K/V, S^T trick -> P stays in registers, PV via 16x16x16 f16 ----------
__global__ __launch_bounds__(256, 4) void attn(const short* __restrict__ Qg,
                                               const short* __restrict__ Kg,
                                               const short* __restrict__ Vt,
                                               short* __restrict__ Opart,
                                               float* __restrict__ Ls) {
    __shared__ short Kbuf[2][64 * 64];
    __shared__ short Vbuf[2][64 * 64];
    int tid = threadIdx.x, lane = tid & 63, wv = tid >> 6;
    int g = lane >> 4, c = lane & 15;

    // decode bid -> (batch, p, ch); reversed so biggest-p blocks dispatch first
    int rb = 1151 - blockIdx.x;
    int batch = rb / 288;
    int j = rb - batch * 288;
    int gq = (int)((sqrtf((float)j + 1.0f) - 1.0f) * 0.5f);
    while (4 * (gq + 1) * (gq + 2) <= j) ++gq;
    while (4 * gq * (gq + 1) > j) --gq;
    int rem = j - 4 * gq * (gq + 1);
    int pidx = rem / (gq + 1);
    int ch = rem - pidx * (gq + 1);
    int p = gq * 8 + pidx;

    int t0 = ch * 8, t1 = min(t0 + 8, p + 1);
    int qrow0 = batch * SS + p * 64;
    const short* Kb = Kg + batch * SS * 64;
    const short* Vb = Vt + batch * SS * 64;

    // Q B-frags (qrow = qrow0 + wv*16 + c)
    short8 aq0 = *reinterpret_cast<const short8*>(Qg + (qrow0 + wv * 16 + c) * 64 + g * 8);
    short8 aq1 = *reinterpret_cast<const short8*>(Qg + (qrow0 + wv * 16 + c) * 64 + 32 + g * 8);

    f32x4 acc_o[4];                       // O^T: [ft] -> feat = ft*16 + g*4 + r, qrow = c
    for (int f = 0; f < 4; ++f) acc_o[f] = (f32x4)(0.f);
    float rs = 0.f;                       // per-lane partial l (qrow=c, keys of this g-group)

    // staging: K source-swizzled (chunk ^ row), V identity (swizzle baked into global layout)
    int s0 = wv * 128 + lane, s1 = s0 + 64;
    int r0 = s0 >> 3, q0 = (s0 & 7) ^ (r0 & 7);
    int r1 = s1 >> 3, q1 = (s1 & 7) ^ (r1 & 7);

#define ATTN_ISSUE(nbs, t)                                                  \
    do {                                                                    \
        glds16(Kb + (t) * 4096 + r0 * 64 + q0 * 8, &Kbuf[nbs][s0 * 8]);     \
        glds16(Kb + (t) * 4096 + r1 * 64 + q1 * 8, &Kbuf[nbs][s1 * 8]);     \
        glds16(Vb + (t) * 4096 + s0 * 8, &Vbuf[nbs][s0 * 8]);               \
        glds16(Vb + (t) * 4096 + s1 * 8, &Vbuf[nbs][s1 * 8]);               \
    } while (0)

    ATTN_ISSUE(0, t0);

    for (int t = t0; t < t1; ++t) {
        int bs = (t - t0) & 1;
        __syncthreads();
        if (t + 1 < t1) ATTN_ISSUE(bs ^ 1, t + 1);

        // S^T = K·Q^T : C-layout holds key = nt*16 + g*4 + r, qrow = c
        f32x4 s[4];
#pragma unroll
        for (int nt = 0; nt < 4; ++nt) {
            short8 k0 = *reinterpret_cast<const short8*>(&Kbuf[bs][(nt * 16 + c) * 64 + ((g) ^ (c & 7)) * 8]);
            short8 k1 = *reinterpret_cast<const short8*>(&Kbuf[bs][(nt * 16 + c) * 64 + ((g + 4) ^ (c & 7)) * 8]);
            s[nt] = (f32x4)(0.f);
            s[nt] = __builtin_amdgcn_mfma_f32_16x16x32_bf16(k0, aq0, s[nt], 0, 0, 0);
            s[nt] = __builtin_amdgcn_mfma_f32_16x16x32_bf16(k1, aq1, s[nt], 0, 0, 0);
        }

        // fixed-max softmax in registers; P^T is directly the 16x16x16 B-operand layout
        half4 pb[4];
        if (t == p) {      // diagonal tile: causal mask (key > qrow)
#pragma unroll
            for (int nt = 0; nt < 4; ++nt)
                for (int r = 0; r < 4; ++r) {
                    int key = nt * 16 + g * 4 + r;
                    int row = wv * 16 + c;
                    float pv = (key <= row) ? __builtin_amdgcn_exp2f(s[nt][r]) : 0.f;
                    rs += pv;
                    pb[nt][r] = (_Float16)pv;
                }
        } else {
#pragma unroll
            for (int nt = 0; nt < 4; ++nt)
                for (int r = 0; r < 4; ++r) {
                    float pv = __builtin_amdgcn_exp2f(s[nt][r]);
                    rs += pv;
                    pb[nt][r] = (_Float16)pv;
                }
        }

        // O^T += V^T · P^T  (A = V^T f16 b64 frags from LDS, B = P^T in regs)
#pragma unroll
        for (int nt = 0; nt < 4; ++nt) {
#pragma unroll
            for (int ft = 0; ft < 4; ++ft) {
                half4 va = *reinterpret_cast<const half4*>(
                    &Vbuf[bs][(ft * 16 + c) * 64 + ((nt * 16 + g * 4) ^ (c * 4))]);
                acc_o[ft] = __builtin_amdgcn_mfma_f32_16x16x16f16(va, pb[nt], acc_o[ft], 0, 0, 0);
            }
        }
    }
#undef ATTN_ISSUE

    // l for qrow=c: sum partials across the 4 g-groups (lanes differing in bits 4-5)
    float l = rs;
    l += __shfl_xor(l, 16);
    l += __shfl_xor(l, 32);
    float inv = 1.0f / l;

    int slot = ((batch * 64 + p) << 3) + ch;
    short* op = Opart + slot * 4096;
    int row = wv * 16 + c;
#pragma unroll
    for (int ft = 0; ft < 4; ++ft) {
        short4 ov;
        ov.x = f2bf(acc_o[ft][0] * inv);
        ov.y = f2bf(acc_o[ft][1] * inv);
        ov.z = f2bf(acc_o[ft][2] * inv);
        ov.w = f2bf(acc_o[ft][3] * inv);
        *reinterpret_cast<short4*>(op + row * 64 + ft * 16 + g * 4) = ov;
    }
    if (g == 0)
        Ls[slot * 64 + wv * 16 + c] = l;
}

// ---------- merge <=8 chunks per (batch,P): out = sum(l_i * O_i) / sum(l_i) ----------
__global__ __launch_bounds__(256) void merge_k(const short* __restrict__ Opart,
                                               const float* __restrict__ Ls,
                                               float* __restrict__ out) {
    int bP = blockIdx.x;               // batch*64 + P
    int P = bP & 63, batch = bP >> 6;
    int nch = (P + 8) >> 3;            // ceil((P+1)/8)
    int tid = threadIdx.x;
    int row = tid & 63, fg = tid >> 6;
    int slot0 = bP << 3;

    float w[8];
    float wsum = 0.f;
    for (int i = 0; i < nch; ++i) { w[i] = Ls[(slot0 + i) * 64 + row]; wsum += w[i]; }
    float invw = 1.0f / wsum;

    float o[16];
    for (int jj = 0; jj < 16; ++jj) o[jj] = 0.f;
    for (int i = 0; i < nch; ++i) {
        const short* op = Opart + (slot0 + i) * 4096 + row * 64 + fg * 16;
        short8 v0 = *reinterpret_cast<const short8*>(op);
        short8 v1 = *reinterpret_cast<const short8*>(op + 8);
        for (int jj = 0; jj < 8; ++jj) {
            o[jj]     += w[i] * bf2f(v0[jj]);
            o[8 + jj] += w[i] * bf2f(v1[jj]);
        }
    }
    int orow = batch * SS + P * 64 + row;
    for (int jj = 0; jj < 16; jj += 4) {
        float4 v;
        v.x = o[jj] * invw; v.y = o[jj + 1] * invw; v.z = o[jj + 2] * invw; v.w = o[jj + 3] * invw;
        *reinterpret_cast<float4*>(out + orow * 64 + fg * 16 + jj) = v;
    }
}

extern "C" void kernel_launch(void* const* d_in, const int* in_sizes, int n_in,
                              void* d_out, int out_size, void* d_ws, size_t ws_size,
                              hipStream_t stream) {
    const float* x  = (const float*)d_in[0];
    const float* Wq = (const float*)d_in[1];
    const float* bq = (const float*)d_in[2];
    const float* Wk = (const float*)d_in[3];
    const float* bk = (const float*)d_in[4];
    const float* Wv = (const float*)d_in[5];
    const float* bv = (const float*)d_in[6];
    float* out = (float*)d_out;

    short* Wpack = (short*)d_ws;                    // 196608 shorts
    short* Qg    = Wpack + 196608;                  // 1048576
    short* Kg    = Qg + NROW * 64;                  // 1048576
    short* Vt    = Kg + NROW * 64;                  // 1048576 (f16, tile-blocked + swizzled)
    short* Opart = Vt + NROW * 64;                  // 2048*4096
    float* Ls    = (float*)(Opart + 2048 * 4096);   // 2048*64 floats

    hipLaunchKernelGGL(pack_w,   dim3(48),   dim3(256), 0, stream, Wq, Wk, Wv, Wpack);
    hipLaunchKernelGGL(proj_qkv, dim3(512),  dim3(256), 0, stream, x, Wpack, bq, bk, bv, Qg, Kg, Vt);
    hipLaunchKernelGGL(attn,     dim3(1152), dim3(256), 0, stream, Qg, Kg, Vt, Opart, Ls);
    hipLaunchKernelGGL(merge_k,  dim3(256),  dim3(256), 0, stream, Opart, Ls, out);
}